// Round 6
// baseline (248.753 us; speedup 1.0000x reference)
//
#include <hip/hip_runtime.h>
#include <stdint.h>

typedef __bf16 bf16x8 __attribute__((ext_vector_type(8)));
typedef float  f32x4  __attribute__((ext_vector_type(4)));

__device__ __forceinline__ uint16_t f32_to_bf16_rne(float f) {
    uint32_t u = __float_as_uint(f);
    uint32_t r = (u + 0x7FFFu + ((u >> 16) & 1u)) >> 16;
    return (uint16_t)r;
}

// ---------------------------------------------------------------------------
// Weight pack (bf16 in d_ws), dense blocked-K row-major:
//   [level][kb][n(272 rows, 267 real)][32 k]  (64 B per row per kb-block)
//   level elem offsets: L0=0 (KB=8), L1=69632 (KB=16), L2=208896 (KB=32)
//   total 487424 elems = 975 KB. Fragment for lane (gq,lc), tile nt, step kb:
//   16B at  PKOFF + kb*8704 + (nt*16+lc)*32 + gq*8   -> k = kb*32 + gq*8 + j.
// ---------------------------------------------------------------------------
__global__ void pack_w(const float* __restrict__ w0, const float* __restrict__ w1,
                       const float* __restrict__ w2, uint16_t* __restrict__ pk) {
    int e = blockIdx.x * 256 + threadIdx.x;
    if (e >= 487424) return;
    int C; const float* w; int base;
    if (e < 69632)       { base = 0;      C = 256;  w = w0; }
    else if (e < 208896) { base = 69632;  C = 512;  w = w1; }
    else                 { base = 208896; C = 1024; w = w2; }
    int r  = e - base;
    int kb = r / 8704;  r -= kb * 8704;
    int n  = r >> 5;    int c = r & 31;       // k_local = c
    uint16_t v = 0;
    if (n < 267) v = f32_to_bf16_rne(w[n * C + kb * 32 + c]);
    pk[e] = v;
}

// ---------------------------------------------------------------------------
// Barrier-free, LDS-free fused GEMM+decode. One wave (64 thr) per block.
// Wave owns m-tiles u=0,1 (32 hw) x 17 n-tiles (272 n, 267 real).
// X: zero reuse -> per-lane direct global loads (16B-coalesced 64B segments),
//    1-step register prefetch. W: L1/L2-resident packed fragments, dwordx4.
// C/D map (16x16x32): col = lane&15 (hw), row = 4*(lane>>4)+reg (n).
// ---------------------------------------------------------------------------
template<int C, int HW, int NX, int ROWOFF, int PKOFF>
__device__ __forceinline__ void gemm_body(
    const float* __restrict__ x, const float* __restrict__ bias,
    const uint16_t* __restrict__ pk, float* __restrict__ out,
    int m0, float stride_,
    float ax0, float ay0, float ax1, float ay1, float ax2, float ay2)
{
    const int l  = threadIdx.x;     // 0..63
    const int gq = l >> 4;
    const int lc = l & 15;

    // per-lane output positions for the two m-tiles (handles batch straddle)
    const int ml0 = m0 + lc;
    const int ml1 = m0 + 16 + lc;
    const int b0i = ml0 / HW; const int hwp0 = ml0 - b0i * HW;
    const int b1i = ml1 / HW; const int hwp1 = ml1 - b1i * HW;

    // X pointers at k = 8*gq (this lane's k-rows are 8*gq + e, e=0..7)
    const float* xp0 = x + (size_t)b0i * C * HW + hwp0 + (size_t)(8 * gq) * HW;
    const float* xp1 = x + (size_t)b1i * C * HW + hwp1 + (size_t)(8 * gq) * HW;

    const uint16_t* wp = pk + PKOFF + lc * 32 + gq * 8;

    f32x4 acc[2][17];
    #pragma unroll
    for (int i = 0; i < 2; ++i)
        #pragma unroll
        for (int j = 0; j < 17; ++j) acc[i][j] = (f32x4){0.f, 0.f, 0.f, 0.f};

    // prefetch X for kb=0
    float xf0[8], xf1[8];
    #pragma unroll
    for (int e = 0; e < 8; ++e) {
        xf0[e] = xp0[(size_t)e * HW];
        xf1[e] = xp1[(size_t)e * HW];
    }

    const int KB = C / 32;
    #pragma unroll 1
    for (int kb = 0; kb < KB; ++kb) {
        // convert current X regs to bf16 frags (HW RNE via v_cvt)
        bf16x8 bfr0, bfr1;
        #pragma unroll
        for (int e = 0; e < 8; ++e) {
            bfr0[e] = (__bf16)xf0[e];
            bfr1[e] = (__bf16)xf1[e];
        }
        // issue next-step X loads early (hide HBM latency under W+MFMA chain)
        if (kb + 1 < KB) {
            const float* n0 = xp0 + (size_t)(kb + 1) * 32 * HW;
            const float* n1 = xp1 + (size_t)(kb + 1) * 32 * HW;
            #pragma unroll
            for (int e = 0; e < 8; ++e) {
                xf0[e] = n0[(size_t)e * HW];
                xf1[e] = n1[(size_t)e * HW];
            }
        }
        // W fragments (L1/L2 hit) + MFMA
        const uint16_t* wrow = wp + kb * 8704;
        #pragma unroll
        for (int nt = 0; nt < 17; ++nt) {
            bf16x8 af = *(const bf16x8*)(wrow + nt * 512);
            acc[0][nt] = __builtin_amdgcn_mfma_f32_16x16x32_bf16(af, bfr0, acc[0][nt], 0, 0, 0);
            acc[1][nt] = __builtin_amdgcn_mfma_f32_16x16x32_bf16(af, bfr1, acc[1][nt], 0, 0, 0);
        }
    }

    // ---- epilogue: decode + scatter store ----
    #pragma unroll
    for (int mt = 0; mt < 2; ++mt) {
        const int bb  = mt ? b1i : b0i;
        const int hwp = mt ? hwp1 : hwp0;
        const int gy  = hwp / NX;
        const int gx  = hwp - gy * NX;
        const int R0  = bb * 25200 + ROWOFF + hwp;
        const float fgx = (float)gx, fgy = (float)gy;
        #pragma unroll
        for (int nt = 0; nt < 17; ++nt) {
            #pragma unroll
            for (int r = 0; r < 4; ++r) {
                const int n = nt * 16 + 4 * gq + r;
                if (nt == 16 && n >= 267) continue;   // folds away for nt<16
                const int a = (n >= 178) ? 2 : (n >= 89 ? 1 : 0);
                const int o = n - a * 89;
                float v = acc[mt][nt][r] + bias[n];
                float y;
                if (o == 0) {
                    y = (__builtin_amdgcn_rcpf(1.0f + __expf(-v)) + fgx) * stride_;
                } else if (o == 1) {
                    y = (__builtin_amdgcn_rcpf(1.0f + __expf(-v)) + fgy) * stride_;
                } else if (o == 2) {
                    float ax = (a == 0) ? ax0 : (a == 1 ? ax1 : ax2);
                    y = __expf(v) * ax;
                } else if (o == 3) {
                    float ay = (a == 0) ? ay0 : (a == 1 ? ay1 : ay2);
                    y = __expf(v) * ay;
                } else {
                    y = __builtin_amdgcn_rcpf(1.0f + __expf(-v));
                }
                out[(size_t)(R0 + a * HW) * 89 + o] = y;
            }
        }
    }
}

__global__ __launch_bounds__(64, 2) void detect_gemm(
    const float* __restrict__ x0, const float* __restrict__ x1, const float* __restrict__ x2,
    const float* __restrict__ b0, const float* __restrict__ b1, const float* __restrict__ b2,
    const uint16_t* __restrict__ pk, float* __restrict__ out)
{
    const int bid = blockIdx.x;
    // longest blocks (level 2, 32 K-steps) first to avoid a serial tail
    if (bid < 100) {
        gemm_body<1024, 400, 20, 24000, 208896>(x2, b2, pk, out, bid * 32, 32.f,
                                                116.f, 90.f, 156.f, 198.f, 373.f, 326.f);
    } else if (bid < 500) {
        gemm_body<512, 1600, 40, 19200, 69632>(x1, b1, pk, out, (bid - 100) * 32, 16.f,
                                               30.f, 61.f, 62.f, 45.f, 59.f, 119.f);
    } else {
        gemm_body<256, 6400, 80, 0, 0>(x0, b0, pk, out, (bid - 500) * 32, 8.f,
                                       10.f, 13.f, 16.f, 30.f, 33.f, 23.f);
    }
}

extern "C" void kernel_launch(void* const* d_in, const int* in_sizes, int n_in,
                              void* d_out, int out_size, void* d_ws, size_t ws_size,
                              hipStream_t stream) {
    (void)in_sizes; (void)n_in; (void)out_size; (void)ws_size;
    const float* x0 = (const float*)d_in[0];
    const float* w0 = (const float*)d_in[1];
    const float* b0 = (const float*)d_in[2];
    const float* x1 = (const float*)d_in[3];
    const float* w1 = (const float*)d_in[4];
    const float* b1 = (const float*)d_in[5];
    const float* x2 = (const float*)d_in[6];
    const float* w2 = (const float*)d_in[7];
    const float* b2 = (const float*)d_in[8];
    uint16_t* pk = (uint16_t*)d_ws;   // 974,848 B used
    float* out = (float*)d_out;

    pack_w<<<1904, 256, 0, stream>>>(w0, w1, w2, pk);
    detect_gemm<<<2100, 64, 0, stream>>>(x0, x1, x2, b0, b1, b2, pk, out);
}